// Round 2
// baseline (112.936 us; speedup 1.0000x reference)
//
#include <hip/hip_runtime.h>

// Bahdanau additive attention: B=8, TE=512, TD=256, H=256, fp32.
//   We = enc @ W_a; Uh = dec @ U_a
//   e[b,j,i] = softmax_i( sum_h V[h]*tanh(We[b,i,h]+Uh[b,j,h]) )
//   c[b,j,h] = sum_i e[b,j,i]*enc[b,i,h]
// d_out = [c (B*TD*H)] ++ [e (B*TD*TE)]
//
// R10 (this round): split the fused k_attn (39.8us, VALUBusy 49% == pure
// structural stall: barrier-locked phases, 16-wave/CU grid cap, softmax
// idling 4/8 waves, barrier drains L2 loads) into:
//   k_energy: barrier-free streaming energies -> E workspace (4MB).
//             Same QSTEP math/order (bit-identical E). unroll 4.
//   k_soft:   E -> LDS, then the old softmax + phase B unchanged.
// R9 keeps: k_pre = split-bf16 MFMA GEMM (x = hi + lo residual;
//   C = Ah*Bh + Ah*Bl + Al*Bh), k_tw = one-shot weight transpose/split.
// R8 keeps: 4-way reciprocal batching (14 full-rate ops + 1 rcp / 4 elems).
// R7 keeps: XCD swizzle (b = blockIdx&7), interleaved W4 layout.

#define BB 8
#define TE 512
#define TD 256
#define HH 256

#define EXP2F(x) __builtin_amdgcn_exp2f(x)
#define RCPF(x)  __builtin_amdgcn_rcpf(x)
#define KSCALE   2.8853900817779268f    // 2*log2(e)
#define NSC      (-2.8853900817779268f) // -2*log2(e)

typedef __attribute__((ext_vector_type(8))) short short8_t;  // 8 bf16 = 4 VGPR
typedef __attribute__((ext_vector_type(4))) float f32x4;     // MFMA acc

__device__ __forceinline__ unsigned short f2bf(float x) {
    unsigned int u = __float_as_uint(x);
    return (unsigned short)((u + 0x7FFFu + ((u >> 16) & 1u)) >> 16);  // RNE
}
__device__ __forceinline__ float bf2f(unsigned short h) {
    return __uint_as_float(((unsigned int)h) << 16);
}

// ---------------------------------------------------------------------------
// k_tw: one-shot transpose+split of the weights.
//   Wt[s][h][k] (bf16 hi/lo) = W_s[k][h],  s=0: Wa (enc), s=1: Ua (dec).
// 32 blocks x 256 threads, 64x64 tiles via LDS.
// ---------------------------------------------------------------------------
__global__ __launch_bounds__(256) void k_tw(
    const float* __restrict__ Wa, const float* __restrict__ Ua,
    unsigned short* __restrict__ Wth, unsigned short* __restrict__ Wtl)
{
    const int t    = threadIdx.x;
    const int s    = blockIdx.x >> 4;
    const int tile = blockIdx.x & 15;
    const int tk   = (tile >> 2) * 64;
    const int th   = (tile & 3) * 64;
    const float* W = s ? Ua : Wa;

    __shared__ float Ls[64][65];
    const int kr = t >> 4;          // 0..15
    const int hc = (t & 15) * 4;    // 0..60
    #pragma unroll
    for (int r = 0; r < 4; r++) {
        float4 v = *(const float4*)(W + (size_t)(tk + kr + 16 * r) * HH + th + hc);
        Ls[kr + 16 * r][hc + 0] = v.x; Ls[kr + 16 * r][hc + 1] = v.y;
        Ls[kr + 16 * r][hc + 2] = v.z; Ls[kr + 16 * r][hc + 3] = v.w;
    }
    __syncthreads();
    const int hr  = t >> 4;
    const int kc4 = (t & 15) * 4;
    #pragma unroll
    for (int r = 0; r < 4; r++) {
        const int hl = hr + 16 * r;
        float f0 = Ls[kc4 + 0][hl], f1 = Ls[kc4 + 1][hl];
        float f2 = Ls[kc4 + 2][hl], f3 = Ls[kc4 + 3][hl];
        ushort4 hi, lo;
        hi.x = f2bf(f0); lo.x = f2bf(f0 - bf2f(hi.x));
        hi.y = f2bf(f1); lo.y = f2bf(f1 - bf2f(hi.y));
        hi.z = f2bf(f2); lo.z = f2bf(f2 - bf2f(hi.z));
        hi.w = f2bf(f3); lo.w = f2bf(f3 - bf2f(hi.w));
        const size_t o = ((size_t)(s * 256 + th + hl)) * 256 + tk + kc4;
        *(ushort4*)(Wth + o) = hi;
        *(ushort4*)(Wtl + o) = lo;
    }
}

// ---------------------------------------------------------------------------
// k_pre: split-bf16 MFMA GEMM over the concatenated rows X = [enc; dec],
// computed as D[h][i] so D-frag rows (4 consecutive h per lane) match both
// output layouts. Tile: 64h x 64i, 4 waves, wave -> 32x32 (2x2 of 16x16),
// K-chunks of 32, reg-prefetch of next chunk. Layouts (m89-verified):
//   A/B frags: row/col = l&15, k-octet = (l>>4)*8; D: col=l&15, row=(l>>4)*4+reg.
// ---------------------------------------------------------------------------
__global__ __launch_bounds__(256) void k_pre(
    const float* __restrict__ enc, const float* __restrict__ dec,
    const unsigned short* __restrict__ Wth, const unsigned short* __restrict__ Wtl,
    float* __restrict__ W4, float* __restrict__ Uhe)
{
    const int t  = threadIdx.x;
    const int it = blockIdx.x >> 2;       // 0..95  (i-tile)
    const int ht = blockIdx.x & 3;        // 0..3   (h-tile)
    const int i0 = it * 64;
    const int h0 = ht * 64;
    const bool is_enc = (i0 < BB * TE);   // < 4096
    const float* X = is_enc ? (enc + (size_t)i0 * HH)
                            : (dec + (size_t)(i0 - BB * TE) * HH);
    const int s = is_enc ? 0 : 1;
    const unsigned short* Ah = Wth + ((size_t)(s * 256 + h0)) * 256;
    const unsigned short* Al = Wtl + ((size_t)(s * 256 + h0)) * 256;

    __shared__ unsigned short At_h[64][40], At_l[64][40];
    __shared__ unsigned short Xs_h[64][40], Xs_l[64][40];

    const int sr = t >> 2;                // staging row 0..63
    const int sq = (t & 3) * 8;           // staging k-octet

    const int wv = t >> 6, l = t & 63;
    const int wh = (wv & 1) * 32;
    const int wi = (wv >> 1) * 32;
    const int fr = l & 15;
    const int fk = (l >> 4) * 8;
    const int rq = l >> 4;                // D row-quad

    f32x4 acc[2][2];
    #pragma unroll
    for (int a0 = 0; a0 < 2; a0++)
        #pragma unroll
        for (int a1 = 0; a1 < 2; a1++)
            acc[a0][a1] = (f32x4){0.f, 0.f, 0.f, 0.f};

    short8_t aH = *(const short8_t*)(Ah + (size_t)sr * 256 + sq);
    short8_t aL = *(const short8_t*)(Al + (size_t)sr * 256 + sq);
    float4   x0 = *(const float4*)(X + (size_t)sr * HH + sq);
    float4   x1 = *(const float4*)(X + (size_t)sr * HH + sq + 4);

    #pragma unroll
    for (int c = 0; c < 8; c++) {
        short8_t xh, xl;
        {
            unsigned short h;
            h = f2bf(x0.x); xh[0] = (short)h; xl[0] = (short)f2bf(x0.x - bf2f(h));
            h = f2bf(x0.y); xh[1] = (short)h; xl[1] = (short)f2bf(x0.y - bf2f(h));
            h = f2bf(x0.z); xh[2] = (short)h; xl[2] = (short)f2bf(x0.z - bf2f(h));
            h = f2bf(x0.w); xh[3] = (short)h; xl[3] = (short)f2bf(x0.w - bf2f(h));
            h = f2bf(x1.x); xh[4] = (short)h; xl[4] = (short)f2bf(x1.x - bf2f(h));
            h = f2bf(x1.y); xh[5] = (short)h; xl[5] = (short)f2bf(x1.y - bf2f(h));
            h = f2bf(x1.z); xh[6] = (short)h; xl[6] = (short)f2bf(x1.z - bf2f(h));
            h = f2bf(x1.w); xh[7] = (short)h; xl[7] = (short)f2bf(x1.w - bf2f(h));
        }
        __syncthreads();
        *(short8_t*)&At_h[sr][sq] = aH;
        *(short8_t*)&At_l[sr][sq] = aL;
        *(short8_t*)&Xs_h[sr][sq] = xh;
        *(short8_t*)&Xs_l[sr][sq] = xl;
        if (c < 7) {
            const int kc = (c + 1) * 32;
            aH = *(const short8_t*)(Ah + (size_t)sr * 256 + kc + sq);
            aL = *(const short8_t*)(Al + (size_t)sr * 256 + kc + sq);
            x0 = *(const float4*)(X + (size_t)sr * HH + kc + sq);
            x1 = *(const float4*)(X + (size_t)sr * HH + kc + sq + 4);
        }
        __syncthreads();
        #pragma unroll
        for (int fm = 0; fm < 2; fm++) {
            short8_t a_h = *(const short8_t*)&At_h[wh + 16 * fm + fr][fk];
            short8_t a_l = *(const short8_t*)&At_l[wh + 16 * fm + fr][fk];
            #pragma unroll
            for (int fn = 0; fn < 2; fn++) {
                short8_t b_h = *(const short8_t*)&Xs_h[wi + 16 * fn + fr][fk];
                short8_t b_l = *(const short8_t*)&Xs_l[wi + 16 * fn + fr][fk];
                acc[fm][fn] = __builtin_amdgcn_mfma_f32_16x16x32_bf16(a_h, b_h, acc[fm][fn], 0, 0, 0);
                acc[fm][fn] = __builtin_amdgcn_mfma_f32_16x16x32_bf16(a_h, b_l, acc[fm][fn], 0, 0, 0);
                acc[fm][fn] = __builtin_amdgcn_mfma_f32_16x16x32_bf16(a_l, b_h, acc[fm][fn], 0, 0, 0);
            }
        }
    }

    #pragma unroll
    for (int fm = 0; fm < 2; fm++) {
        #pragma unroll
        for (int fn = 0; fn < 2; fn++) {
            f32x4 v = acc[fm][fn];
            float4 o;
            o.x = EXP2F(v[0] * KSCALE);
            o.y = EXP2F(v[1] * KSCALE);
            o.z = EXP2F(v[2] * KSCALE);
            o.w = EXP2F(v[3] * KSCALE);
            const int ig = i0 + wi + 16 * fn + fr;      // global concat row
            const int hb = h0 + wh + 16 * fm + rq * 4;  // 4 consecutive h
            if (is_enc) {
                const int b  = ig >> 9;                 // 512 enc rows/batch
                const int ib = ig & 511;
                const int hq = hb >> 2;
                *(float4*)(W4 + (((size_t)b * 64 + hq) * TE + ib) * 4) = o;
            } else {
                const int j = ig - BB * TE;             // global dec row
                *(float4*)(Uhe + (size_t)j * HH + hb) = o;
            }
        }
    }
}

// ---------------------------------------------------------------------------
// k_energy: barrier-free streaming energies.
// Block = (b = blockIdx&7 [XCD-local], j-group of 4, i-half of 256).
// 256 threads; lane owns one i, 4 j-accumulator chains (keeps W4 read
// traffic at 268MB total, same as fused version). Per q: 1 global b128 (W4)
// + uniform s_loads (Uhe, Va) + 4-way batched reciprocal per j.
// Writes E[b*TD+j][i] = NSC * acc (log2-domain energy), bit-identical to
// the fused kernel's sP values.
// ---------------------------------------------------------------------------
__global__ __launch_bounds__(256) void k_energy(
    const float* __restrict__ W4, const float* __restrict__ Uhe,
    const float* __restrict__ Va, float* __restrict__ E)
{
    const int t  = threadIdx.x;
    const int b  = blockIdx.x & 7;           // XCD-local batch
    const int jg = (blockIdx.x >> 3) & 63;   // j-group
    const int ih = blockIdx.x >> 9;          // i-half
    const int jj0 = b * TD + jg * 4;
    const int i   = ih * 256 + t;

    const float* wp = W4 + ((size_t)b * 64 * TE + i) * 4;
    const float* ua = Uhe + (size_t)jj0 * HH;    // block-uniform -> s_load
    const float* va = Va;                         // uniform

    float a0 = 0.f, a1 = 0.f, a2 = 0.f, a3 = 0.f;

#define QSTEP(ACC, U)                                                     \
    {                                                                     \
        float A_ = fmaf(w4.x, (U).x, 1.f);                                \
        float B_ = fmaf(w4.y, (U).y, 1.f);                                \
        float C_ = fmaf(w4.z, (U).z, 1.f);                                \
        float D_ = fmaf(w4.w, (U).w, 1.f);                                \
        float dAB = A_ * B_, dCD = C_ * D_;                               \
        float nAB = fmaf(v4.x, B_, v4.y * A_);                            \
        float nCD = fmaf(v4.z, D_, v4.w * C_);                            \
        float num = fmaf(nAB, dCD, nCD * dAB);                            \
        ACC = fmaf(num, RCPF(dAB * dCD), ACC);                            \
    }

    #pragma unroll 4
    for (int q = 0; q < 64; q++) {
        float4 w4 = *(const float4*)(wp + (size_t)q * TE * 4);
        float4 v4 = *(const float4*)(va + 4 * q);
        float4 u0 = *(const float4*)(ua + 4 * q);
        float4 u1 = *(const float4*)(ua + HH + 4 * q);
        float4 u2 = *(const float4*)(ua + 2 * HH + 4 * q);
        float4 u3 = *(const float4*)(ua + 3 * HH + 4 * q);
        QSTEP(a0, u0)
        QSTEP(a1, u1)
        QSTEP(a2, u2)
        QSTEP(a3, u3)
    }
#undef QSTEP

    float* ep = E + (size_t)jj0 * TE + i;
    ep[0]          = NSC * a0;
    ep[TE]         = NSC * a1;
    ep[2 * TE]     = NSC * a2;
    ep[3 * TE]     = NSC * a3;
}

// ---------------------------------------------------------------------------
// k_soft: E -> LDS, then the previous kernel's softmax + phase B unchanged.
// 512 threads = 8 waves; block owns 4 consecutive j's of ONE batch,
// batch = blockIdx&7 (XCD-local). Softmax: waves 0-3 (one j each).
// Phase B: wave w -> i in [64w,64w+64), all 4 j; 32 KB LDS reduce.
// ---------------------------------------------------------------------------
__global__ __launch_bounds__(512) void k_soft(
    const float* __restrict__ enc, const float* __restrict__ E,
    float* __restrict__ out_c, float* __restrict__ out_e)
{
    const int t  = threadIdx.x;
    const int wv = t >> 6, lane = t & 63;
    const int b   = blockIdx.x & 7;           // XCD-local batch
    const int j0  = (blockIdx.x >> 3) * 4;    // 64 j-groups per batch
    const int jj0 = b * TD + j0;              // block-uniform

    __shared__ float sP[4][TE];      // 8 KB: energies -> probabilities
    __shared__ float sR[8][4][HH];   // 32 KB: phase-B partials

    // load the block's 4 E rows (2048 floats) -> sP
    {
        const float* ep = E + (size_t)jj0 * TE;
        float4 v = *(const float4*)(ep + t * 4);
        *(float4*)&((float*)sP)[t * 4] = v;
    }
    __syncthreads();

    // ---- softmax: wave w in 0..3 handles j0+w ----------------------------
    if (wv < 4) {
        float ev[8];
        float m = -3.0e38f;
        #pragma unroll
        for (int k = 0; k < 8; k++) {
            ev[k] = sP[wv][lane + 64 * k];
            m = fmaxf(m, ev[k]);
        }
        #pragma unroll
        for (int off = 32; off; off >>= 1) m = fmaxf(m, __shfl_xor(m, off, 64));
        float s = 0.f;
        #pragma unroll
        for (int k = 0; k < 8; k++) { ev[k] = EXP2F(ev[k] - m); s += ev[k]; }
        #pragma unroll
        for (int off = 32; off; off >>= 1) s += __shfl_xor(s, off, 64);
        float rs = RCPF(s);
        float* oe = out_e + (size_t)(jj0 + wv) * TE;
        #pragma unroll
        for (int k = 0; k < 8; k++) {
            float p = ev[k] * rs;
            sP[wv][lane + 64 * k] = p;
            oe[lane + 64 * k] = p;
        }
    }
    __syncthreads();

    // ---- Phase B: wave w -> i in [64w, 64w+64), all 4 j ------------------
    const int ib = wv << 6;
    const float* eb = enc + ((size_t)b * TE + ib) * HH + 4 * lane;
    float4 c0 = {0,0,0,0}, c1 = {0,0,0,0}, c2 = {0,0,0,0}, c3 = {0,0,0,0};
    #pragma unroll 2
    for (int k = 0; k < 64; k++) {
        float p0 = sP[0][ib + k];   // uniform broadcasts
        float p1 = sP[1][ib + k];
        float p2 = sP[2][ib + k];
        float p3 = sP[3][ib + k];
        float4 q = *(const float4*)(eb + (size_t)k * HH);
        c0.x = fmaf(p0, q.x, c0.x); c0.y = fmaf(p0, q.y, c0.y);
        c0.z = fmaf(p0, q.z, c0.z); c0.w = fmaf(p0, q.w, c0.w);
        c1.x = fmaf(p1, q.x, c1.x); c1.y = fmaf(p1, q.y, c1.y);
        c1.z = fmaf(p1, q.z, c1.z); c1.w = fmaf(p1, q.w, c1.w);
        c2.x = fmaf(p2, q.x, c2.x); c2.y = fmaf(p2, q.y, c2.y);
        c2.z = fmaf(p2, q.z, c2.z); c2.w = fmaf(p2, q.w, c2.w);
        c3.x = fmaf(p3, q.x, c3.x); c3.y = fmaf(p3, q.y, c3.y);
        c3.z = fmaf(p3, q.z, c3.z); c3.w = fmaf(p3, q.w, c3.w);
    }
    *(float4*)&sR[wv][0][4 * lane] = c0;
    *(float4*)&sR[wv][1][4 * lane] = c1;
    *(float4*)&sR[wv][2][4 * lane] = c2;
    *(float4*)&sR[wv][3][4 * lane] = c3;
    __syncthreads();

    // ---- final reduce: wave w -> (j = w&3, h-half = w>>2) ----------------
    {
        const int jr = wv & 3;
        const int h2 = (wv >> 2) * 128 + 2 * lane;
        float sx = 0.f, sy = 0.f;
        #pragma unroll
        for (int ww = 0; ww < 8; ww++) {
            float2 tv = *(const float2*)&sR[ww][jr][h2];
            sx += tv.x; sy += tv.y;
        }
        float2 o; o.x = sx; o.y = sy;
        *(float2*)(out_c + (size_t)(jj0 + jr) * HH + h2) = o;
    }
}

extern "C" void kernel_launch(void* const* d_in, const int* in_sizes, int n_in,
                              void* d_out, int out_size, void* d_ws, size_t ws_size,
                              hipStream_t stream) {
    const float* enc = (const float*)d_in[0];
    const float* dec = (const float*)d_in[1];
    const float* Wa  = (const float*)d_in[2];
    const float* Ua  = (const float*)d_in[3];
    const float* Va  = (const float*)d_in[4];

    float* W4  = (float*)d_ws;                        // exp2-domain, interleaved
    float* Uhe = W4 + (size_t)BB * HH * TE;           // exp2-domain, B*TD*H
    unsigned short* Wth = (unsigned short*)(Uhe + (size_t)BB * TD * HH); // W^T hi
    unsigned short* Wtl = Wth + 2 * 256 * 256;                           // W^T lo
    float* Ew = (float*)(Wtl + 2 * 256 * 256);        // energies, B*TD*TE (4MB)

    float* out_c = (float*)d_out;                     // [B,TD,H]
    float* out_e = out_c + (size_t)BB * TD * HH;      // [B,TD,TE]

    k_tw<<<32, 256, 0, stream>>>(Wa, Ua, Wth, Wtl);
    k_pre<<<384, 256, 0, stream>>>(enc, dec, Wth, Wtl, W4, Uhe);
    k_energy<<<BB * 64 * 2, 256, 0, stream>>>(W4, Uhe, Va, Ew);
    k_soft<<<BB * TD / 4, 512, 0, stream>>>(enc, Ew, out_c, out_e);
}

// Round 3
// 107.395 us; speedup vs baseline: 1.0516x; 1.0516x over previous
//
#include <hip/hip_runtime.h>

// Bahdanau additive attention: B=8, TE=512, TD=256, H=256, fp32.
//   We = enc @ W_a; Uh = dec @ U_a
//   e[b,j,i] = softmax_i( sum_h V[h]*tanh(We[b,i,h]+Uh[b,j,h]) )
//   c[b,j,h] = sum_i e[b,j,i]*enc[b,i,h]
// d_out = [c (B*TD*H)] ++ [e (B*TD*TE)]
//
// R11 (this round): revert R10's split (it was +5us pure overhead; barrier
// theory refuted) back to the fused k_attn, and attack the REAL stall:
// VGPR_Count=28 showed the compiler had zero prefetch registers -> every
// w4/enc load exposed ~200cy L2 latency (VALUBusy 49%). Phase A and phase B
// now have explicit 2-deep, manually-2-unrolled software pipelines with
// named prefetch regs. Arithmetic order unchanged (bit-identical absmax).
// R9 keeps: k_pre = split-bf16 MFMA GEMM (C = Ah*Bh + Ah*Bl + Al*Bh),
//   k_tw = one-shot weight transpose/split.
// R8 keeps: 4-way reciprocal batching (14 full-rate ops + 1 rcp / 4 elems).
// R7 keeps: XCD swizzle (b = blockIdx&7), interleaved W4 layout.

#define BB 8
#define TE 512
#define TD 256
#define HH 256

#define EXP2F(x) __builtin_amdgcn_exp2f(x)
#define RCPF(x)  __builtin_amdgcn_rcpf(x)
#define KSCALE   2.8853900817779268f    // 2*log2(e)
#define NSC      (-2.8853900817779268f) // -2*log2(e)

typedef __attribute__((ext_vector_type(8))) short short8_t;  // 8 bf16 = 4 VGPR
typedef __attribute__((ext_vector_type(4))) float f32x4;     // MFMA acc

__device__ __forceinline__ unsigned short f2bf(float x) {
    unsigned int u = __float_as_uint(x);
    return (unsigned short)((u + 0x7FFFu + ((u >> 16) & 1u)) >> 16);  // RNE
}
__device__ __forceinline__ float bf2f(unsigned short h) {
    return __uint_as_float(((unsigned int)h) << 16);
}

// ---------------------------------------------------------------------------
// k_tw: one-shot transpose+split of the weights.
//   Wt[s][h][k] (bf16 hi/lo) = W_s[k][h],  s=0: Wa (enc), s=1: Ua (dec).
// 32 blocks x 256 threads, 64x64 tiles via LDS.
// ---------------------------------------------------------------------------
__global__ __launch_bounds__(256) void k_tw(
    const float* __restrict__ Wa, const float* __restrict__ Ua,
    unsigned short* __restrict__ Wth, unsigned short* __restrict__ Wtl)
{
    const int t    = threadIdx.x;
    const int s    = blockIdx.x >> 4;
    const int tile = blockIdx.x & 15;
    const int tk   = (tile >> 2) * 64;
    const int th   = (tile & 3) * 64;
    const float* W = s ? Ua : Wa;

    __shared__ float Ls[64][65];
    const int kr = t >> 4;          // 0..15
    const int hc = (t & 15) * 4;    // 0..60
    #pragma unroll
    for (int r = 0; r < 4; r++) {
        float4 v = *(const float4*)(W + (size_t)(tk + kr + 16 * r) * HH + th + hc);
        Ls[kr + 16 * r][hc + 0] = v.x; Ls[kr + 16 * r][hc + 1] = v.y;
        Ls[kr + 16 * r][hc + 2] = v.z; Ls[kr + 16 * r][hc + 3] = v.w;
    }
    __syncthreads();
    const int hr  = t >> 4;
    const int kc4 = (t & 15) * 4;
    #pragma unroll
    for (int r = 0; r < 4; r++) {
        const int hl = hr + 16 * r;
        float f0 = Ls[kc4 + 0][hl], f1 = Ls[kc4 + 1][hl];
        float f2 = Ls[kc4 + 2][hl], f3 = Ls[kc4 + 3][hl];
        ushort4 hi, lo;
        hi.x = f2bf(f0); lo.x = f2bf(f0 - bf2f(hi.x));
        hi.y = f2bf(f1); lo.y = f2bf(f1 - bf2f(hi.y));
        hi.z = f2bf(f2); lo.z = f2bf(f2 - bf2f(hi.z));
        hi.w = f2bf(f3); lo.w = f2bf(f3 - bf2f(hi.w));
        const size_t o = ((size_t)(s * 256 + th + hl)) * 256 + tk + kc4;
        *(ushort4*)(Wth + o) = hi;
        *(ushort4*)(Wtl + o) = lo;
    }
}

// ---------------------------------------------------------------------------
// k_pre: split-bf16 MFMA GEMM over the concatenated rows X = [enc; dec],
// computed as D[h][i] so D-frag rows (4 consecutive h per lane) match both
// output layouts. Tile: 64h x 64i, 4 waves, wave -> 32x32 (2x2 of 16x16),
// K-chunks of 32, reg-prefetch of next chunk. Layouts (m89-verified):
//   A/B frags: row/col = l&15, k-octet = (l>>4)*8; D: col=l&15, row=(l>>4)*4+reg.
// ---------------------------------------------------------------------------
__global__ __launch_bounds__(256) void k_pre(
    const float* __restrict__ enc, const float* __restrict__ dec,
    const unsigned short* __restrict__ Wth, const unsigned short* __restrict__ Wtl,
    float* __restrict__ W4, float* __restrict__ Uhe)
{
    const int t  = threadIdx.x;
    const int it = blockIdx.x >> 2;       // 0..95  (i-tile)
    const int ht = blockIdx.x & 3;        // 0..3   (h-tile)
    const int i0 = it * 64;
    const int h0 = ht * 64;
    const bool is_enc = (i0 < BB * TE);   // < 4096
    const float* X = is_enc ? (enc + (size_t)i0 * HH)
                            : (dec + (size_t)(i0 - BB * TE) * HH);
    const int s = is_enc ? 0 : 1;
    const unsigned short* Ah = Wth + ((size_t)(s * 256 + h0)) * 256;
    const unsigned short* Al = Wtl + ((size_t)(s * 256 + h0)) * 256;

    __shared__ unsigned short At_h[64][40], At_l[64][40];
    __shared__ unsigned short Xs_h[64][40], Xs_l[64][40];

    const int sr = t >> 2;                // staging row 0..63
    const int sq = (t & 3) * 8;           // staging k-octet

    const int wv = t >> 6, l = t & 63;
    const int wh = (wv & 1) * 32;
    const int wi = (wv >> 1) * 32;
    const int fr = l & 15;
    const int fk = (l >> 4) * 8;
    const int rq = l >> 4;                // D row-quad

    f32x4 acc[2][2];
    #pragma unroll
    for (int a0 = 0; a0 < 2; a0++)
        #pragma unroll
        for (int a1 = 0; a1 < 2; a1++)
            acc[a0][a1] = (f32x4){0.f, 0.f, 0.f, 0.f};

    short8_t aH = *(const short8_t*)(Ah + (size_t)sr * 256 + sq);
    short8_t aL = *(const short8_t*)(Al + (size_t)sr * 256 + sq);
    float4   x0 = *(const float4*)(X + (size_t)sr * HH + sq);
    float4   x1 = *(const float4*)(X + (size_t)sr * HH + sq + 4);

    #pragma unroll
    for (int c = 0; c < 8; c++) {
        short8_t xh, xl;
        {
            unsigned short h;
            h = f2bf(x0.x); xh[0] = (short)h; xl[0] = (short)f2bf(x0.x - bf2f(h));
            h = f2bf(x0.y); xh[1] = (short)h; xl[1] = (short)f2bf(x0.y - bf2f(h));
            h = f2bf(x0.z); xh[2] = (short)h; xl[2] = (short)f2bf(x0.z - bf2f(h));
            h = f2bf(x0.w); xh[3] = (short)h; xl[3] = (short)f2bf(x0.w - bf2f(h));
            h = f2bf(x1.x); xh[4] = (short)h; xl[4] = (short)f2bf(x1.x - bf2f(h));
            h = f2bf(x1.y); xh[5] = (short)h; xl[5] = (short)f2bf(x1.y - bf2f(h));
            h = f2bf(x1.z); xh[6] = (short)h; xl[6] = (short)f2bf(x1.z - bf2f(h));
            h = f2bf(x1.w); xh[7] = (short)h; xl[7] = (short)f2bf(x1.w - bf2f(h));
        }
        __syncthreads();
        *(short8_t*)&At_h[sr][sq] = aH;
        *(short8_t*)&At_l[sr][sq] = aL;
        *(short8_t*)&Xs_h[sr][sq] = xh;
        *(short8_t*)&Xs_l[sr][sq] = xl;
        if (c < 7) {
            const int kc = (c + 1) * 32;
            aH = *(const short8_t*)(Ah + (size_t)sr * 256 + kc + sq);
            aL = *(const short8_t*)(Al + (size_t)sr * 256 + kc + sq);
            x0 = *(const float4*)(X + (size_t)sr * HH + kc + sq);
            x1 = *(const float4*)(X + (size_t)sr * HH + kc + sq + 4);
        }
        __syncthreads();
        #pragma unroll
        for (int fm = 0; fm < 2; fm++) {
            short8_t a_h = *(const short8_t*)&At_h[wh + 16 * fm + fr][fk];
            short8_t a_l = *(const short8_t*)&At_l[wh + 16 * fm + fr][fk];
            #pragma unroll
            for (int fn = 0; fn < 2; fn++) {
                short8_t b_h = *(const short8_t*)&Xs_h[wi + 16 * fn + fr][fk];
                short8_t b_l = *(const short8_t*)&Xs_l[wi + 16 * fn + fr][fk];
                acc[fm][fn] = __builtin_amdgcn_mfma_f32_16x16x32_bf16(a_h, b_h, acc[fm][fn], 0, 0, 0);
                acc[fm][fn] = __builtin_amdgcn_mfma_f32_16x16x32_bf16(a_h, b_l, acc[fm][fn], 0, 0, 0);
                acc[fm][fn] = __builtin_amdgcn_mfma_f32_16x16x32_bf16(a_l, b_h, acc[fm][fn], 0, 0, 0);
            }
        }
    }

    #pragma unroll
    for (int fm = 0; fm < 2; fm++) {
        #pragma unroll
        for (int fn = 0; fn < 2; fn++) {
            f32x4 v = acc[fm][fn];
            float4 o;
            o.x = EXP2F(v[0] * KSCALE);
            o.y = EXP2F(v[1] * KSCALE);
            o.z = EXP2F(v[2] * KSCALE);
            o.w = EXP2F(v[3] * KSCALE);
            const int ig = i0 + wi + 16 * fn + fr;      // global concat row
            const int hb = h0 + wh + 16 * fm + rq * 4;  // 4 consecutive h
            if (is_enc) {
                const int b  = ig >> 9;                 // 512 enc rows/batch
                const int ib = ig & 511;
                const int hq = hb >> 2;
                *(float4*)(W4 + (((size_t)b * 64 + hq) * TE + ib) * 4) = o;
            } else {
                const int j = ig - BB * TE;             // global dec row
                *(float4*)(Uhe + (size_t)j * HH + hb) = o;
            }
        }
    }
}

// ---------------------------------------------------------------------------
// k_attn (fused, R11): 512 threads = 8 waves; block owns 4 consecutive j's
// of ONE batch, batch = blockIdx&7 (XCD-local).
// Phase A: wave w -> i = 64w+lane; explicit 2-deep prefetch of the w4
// stream (named regs wA..wD, manual 2-unroll) so L2 latency hides under
// QSTEP compute. OOB prefetch at q=62 lands in the adjacent Uhe workspace
// region (safe, unused). Softmax: waves 0-3. Phase B: same 2-deep prefetch
// on the enc stream (tail clamped — enc is an input buffer).
// ---------------------------------------------------------------------------
__global__ __launch_bounds__(512) void k_attn(
    const float* __restrict__ enc, const float* __restrict__ W4,
    const float* __restrict__ Uhe, const float* __restrict__ Va,
    float* __restrict__ out_c, float* __restrict__ out_e)
{
    const int wv = threadIdx.x >> 6, lane = threadIdx.x & 63;
    const int b   = blockIdx.x & 7;           // XCD-local batch
    const int j0  = (blockIdx.x >> 3) * 4;    // 64 j-groups per batch
    const int jj0 = b * TD + j0;              // block-uniform

    __shared__ float sP[4][TE];      // 8 KB: energies -> probabilities
    __shared__ float sR[8][4][HH];   // 32 KB: phase-B partials

    const int i = (wv << 6) + lane;
    const float* wp = W4 + ((size_t)b * 64 * TE + i) * 4;
    const float* ua = Uhe + (size_t)jj0 * HH;   // block-uniform -> s_load
    const float* va = Va;                        // uniform

    float a0 = 0.f, a1 = 0.f, a2 = 0.f, a3 = 0.f;

    // 4-way batched reciprocal:
    //   sum_k v_k/A_k = (nAB*dCD + nCD*dAB) / (dAB*dCD),
    //   A=1+wx*ux.., dAB=A*B, nAB=vx*B+vy*A, ...
#define QSTEP(ACC, U)                                                     \
    {                                                                     \
        float A_ = fmaf(w4.x, (U).x, 1.f);                                \
        float B_ = fmaf(w4.y, (U).y, 1.f);                                \
        float C_ = fmaf(w4.z, (U).z, 1.f);                                \
        float D_ = fmaf(w4.w, (U).w, 1.f);                                \
        float dAB = A_ * B_, dCD = C_ * D_;                               \
        float nAB = fmaf(v4.x, B_, v4.y * A_);                            \
        float nCD = fmaf(v4.z, D_, v4.w * C_);                            \
        float num = fmaf(nAB, dCD, nCD * dAB);                            \
        ACC = fmaf(num, RCPF(dAB * dCD), ACC);                            \
    }

#define ASTEP(Q, W4V)                                                     \
    {                                                                     \
        float4 w4 = W4V;                                                  \
        float4 v4 = *(const float4*)(va + 4 * (Q));                       \
        float4 u0 = *(const float4*)(ua + 4 * (Q));                       \
        float4 u1 = *(const float4*)(ua + HH + 4 * (Q));                  \
        float4 u2 = *(const float4*)(ua + 2 * HH + 4 * (Q));              \
        float4 u3 = *(const float4*)(ua + 3 * HH + 4 * (Q));              \
        QSTEP(a0, u0)                                                     \
        QSTEP(a1, u1)                                                     \
        QSTEP(a2, u2)                                                     \
        QSTEP(a3, u3)                                                     \
    }

    // 2-deep software pipeline on the per-lane w4 stream
    float4 wA = *(const float4*)(wp);
    float4 wB = *(const float4*)(wp + (size_t)TE * 4);
    for (int q = 0; q < 64; q += 2) {
        float4 wC = *(const float4*)(wp + (size_t)(q + 2) * TE * 4);
        float4 wD = *(const float4*)(wp + (size_t)(q + 3) * TE * 4);
        ASTEP(q, wA)
        ASTEP(q + 1, wB)
        wA = wC; wB = wD;
    }
#undef ASTEP
#undef QSTEP

    // conflict-free b32 writes (lane-stride 4B), energies in log2 domain
    sP[0][i] = NSC * a0;
    sP[1][i] = NSC * a1;
    sP[2][i] = NSC * a2;
    sP[3][i] = NSC * a3;
    __syncthreads();

    // ---- softmax: wave w in 0..3 handles j0+w ----------------------------
    if (wv < 4) {
        float ev[8];
        float m = -3.0e38f;
        #pragma unroll
        for (int k = 0; k < 8; k++) {
            ev[k] = sP[wv][lane + 64 * k];
            m = fmaxf(m, ev[k]);
        }
        #pragma unroll
        for (int off = 32; off; off >>= 1) m = fmaxf(m, __shfl_xor(m, off, 64));
        float s = 0.f;
        #pragma unroll
        for (int k = 0; k < 8; k++) { ev[k] = EXP2F(ev[k] - m); s += ev[k]; }
        #pragma unroll
        for (int off = 32; off; off >>= 1) s += __shfl_xor(s, off, 64);
        float rs = RCPF(s);
        float* oe = out_e + (size_t)(jj0 + wv) * TE;
        #pragma unroll
        for (int k = 0; k < 8; k++) {
            float p = ev[k] * rs;
            sP[wv][lane + 64 * k] = p;
            oe[lane + 64 * k] = p;
        }
    }
    __syncthreads();

    // ---- Phase B: wave w -> i in [64w, 64w+64), all 4 j ------------------
    const int ib = wv << 6;
    const float* eb = enc + ((size_t)b * TE + ib) * HH + 4 * lane;
    float4 c0 = {0,0,0,0}, c1 = {0,0,0,0}, c2 = {0,0,0,0}, c3 = {0,0,0,0};

#define BSTEP(K, QV)                                                      \
    {                                                                     \
        float p0 = sP[0][ib + (K)];                                       \
        float p1 = sP[1][ib + (K)];                                       \
        float p2 = sP[2][ib + (K)];                                       \
        float p3 = sP[3][ib + (K)];                                       \
        float4 q = QV;                                                    \
        c0.x = fmaf(p0, q.x, c0.x); c0.y = fmaf(p0, q.y, c0.y);           \
        c0.z = fmaf(p0, q.z, c0.z); c0.w = fmaf(p0, q.w, c0.w);           \
        c1.x = fmaf(p1, q.x, c1.x); c1.y = fmaf(p1, q.y, c1.y);           \
        c1.z = fmaf(p1, q.z, c1.z); c1.w = fmaf(p1, q.w, c1.w);           \
        c2.x = fmaf(p2, q.x, c2.x); c2.y = fmaf(p2, q.y, c2.y);           \
        c2.z = fmaf(p2, q.z, c2.z); c2.w = fmaf(p2, q.w, c2.w);           \
        c3.x = fmaf(p3, q.x, c3.x); c3.y = fmaf(p3, q.y, c3.y);           \
        c3.z = fmaf(p3, q.z, c3.z); c3.w = fmaf(p3, q.w, c3.w);           \
    }

    // 2-deep software pipeline on the per-lane enc stream (tail clamped:
    // enc is an input buffer, no OOB reads allowed)
    float4 qA = *(const float4*)(eb);
    float4 qB = *(const float4*)(eb + (size_t)HH);
    for (int k = 0; k < 64; k += 2) {
        const int k2 = (k + 2 < 64) ? k + 2 : 62;
        const int k3 = (k + 3 < 64) ? k + 3 : 63;
        float4 qC = *(const float4*)(eb + (size_t)k2 * HH);
        float4 qD = *(const float4*)(eb + (size_t)k3 * HH);
        BSTEP(k, qA)
        BSTEP(k + 1, qB)
        qA = qC; qB = qD;
    }
#undef BSTEP

    *(float4*)&sR[wv][0][4 * lane] = c0;
    *(float4*)&sR[wv][1][4 * lane] = c1;
    *(float4*)&sR[wv][2][4 * lane] = c2;
    *(float4*)&sR[wv][3][4 * lane] = c3;
    __syncthreads();

    // ---- final reduce: wave w -> (j = w&3, h-half = w>>2) ----------------
    {
        const int jr = wv & 3;
        const int h2 = (wv >> 2) * 128 + 2 * lane;
        float sx = 0.f, sy = 0.f;
        #pragma unroll
        for (int ww = 0; ww < 8; ww++) {
            float2 tv = *(const float2*)&sR[ww][jr][h2];
            sx += tv.x; sy += tv.y;
        }
        float2 o; o.x = sx; o.y = sy;
        *(float2*)(out_c + (size_t)(jj0 + jr) * HH + h2) = o;
    }
}

extern "C" void kernel_launch(void* const* d_in, const int* in_sizes, int n_in,
                              void* d_out, int out_size, void* d_ws, size_t ws_size,
                              hipStream_t stream) {
    const float* enc = (const float*)d_in[0];
    const float* dec = (const float*)d_in[1];
    const float* Wa  = (const float*)d_in[2];
    const float* Ua  = (const float*)d_in[3];
    const float* Va  = (const float*)d_in[4];

    float* W4  = (float*)d_ws;                        // exp2-domain, interleaved
    float* Uhe = W4 + (size_t)BB * HH * TE;           // exp2-domain, B*TD*H
    unsigned short* Wth = (unsigned short*)(Uhe + (size_t)BB * TD * HH); // W^T hi
    unsigned short* Wtl = Wth + 2 * 256 * 256;                           // W^T lo

    float* out_c = (float*)d_out;                     // [B,TD,H]
    float* out_e = out_c + (size_t)BB * TD * HH;      // [B,TD,TE]

    k_tw<<<32, 256, 0, stream>>>(Wa, Ua, Wth, Wtl);
    k_pre<<<384, 256, 0, stream>>>(enc, dec, Wth, Wtl, W4, Uhe);
    k_attn<<<BB * TD / 4, 512, 0, stream>>>(enc, W4, Uhe, Va, out_c, out_e);
}